// Round 1
// baseline (178.734 us; speedup 1.0000x reference)
//
#include <hip/hip_runtime.h>

typedef __attribute__((ext_vector_type(8))) __bf16 bf16x8;
typedef __attribute__((ext_vector_type(4))) float f32x4;
typedef unsigned short u16;

__device__ __forceinline__ float bf2f(u16 h) {
    return __uint_as_float(((unsigned int)h) << 16);
}
__device__ __forceinline__ u16 f2bf(float f) {
    unsigned int u = __float_as_uint(f);
    u += 0x7fffu + ((u >> 16) & 1u);   // RNE
    return (u16)(u >> 16);
}

#define GLOAD_LDS16(gsrc, ldst)                                                          \
    __builtin_amdgcn_global_load_lds(                                                    \
        (__attribute__((address_space(1))) unsigned int*)(gsrc),                         \
        (__attribute__((address_space(3))) unsigned int*)(ldst), 16, 0, 0)

// ---------------------------------------------------------------------------
// Fused f32 -> bf16 convert with zero-padding to (Npad, Kpad)
// ---------------------------------------------------------------------------
struct CvtDesc { const float* src; u16* dst; int N, K, Npad, Kpad, blk0; };
struct CvtTab { CvtDesc t[10]; };

__global__ __launch_bounds__(256) void cvt_all(CvtTab tab) {
    int b = blockIdx.x;
    int ti = 0;
#pragma unroll
    for (int j = 1; j < 10; ++j)
        if (b >= tab.t[j].blk0) ti = j;
    const CvtDesc c = tab.t[ti];
    long i = (long)(b - c.blk0) * 256 + threadIdx.x;
    long tot = (long)c.Npad * c.Kpad;
    if (i >= tot) return;
    int n = (int)(i / c.Kpad);
    int k = (int)(i - (long)n * c.Kpad);
    float v = (n < c.N && k < c.K) ? c.src[(long)n * c.K + k] : 0.f;
    c.dst[i] = f2bf(v);
}

// ---------------------------------------------------------------------------
// bf16 MFMA GEMM: out[m][n] = epilogue( sum_k A[m][k] * W[n][k] + bias[n] )
// BM=BN=BK=64, 256 threads (4 waves as 2x2), 16x16x32 MFMA.
// LDS tiles [64][64] bf16, XOR-swizzled granules (byte ^= (row&7)<<4) via
// pre-swizzled global source + linear global_load_lds dest (rule 21).
// ---------------------------------------------------------------------------
template<int RELU, int HASRES, int OUTF32>
__global__ __launch_bounds__(256) void gemm_k(
    const u16* __restrict__ A, int lda,
    const u16* __restrict__ W, int ldw,
    const float* __restrict__ bias, int Nreal,
    u16* __restrict__ outB, int ldo,
    const u16* __restrict__ res,
    float* __restrict__ outF, const float* __restrict__ addF,
    int nk)
{
    __shared__ __align__(16) char lds[16384];
    char* ldsA = lds;
    char* ldsB = lds + 8192;

    const int tid  = threadIdx.x;
    const int wave = tid >> 6;
    const int lane = tid & 63;
    const int wr = wave >> 1, wc = wave & 1;
    const int lr = lane & 15, lk = lane >> 4;
    const int mb = blockIdx.x * 64;
    const int nb = blockIdx.y * 64;

    f32x4 acc[2][2];
#pragma unroll
    for (int i = 0; i < 2; ++i)
#pragma unroll
        for (int j = 0; j < 2; ++j)
#pragma unroll
            for (int e = 0; e < 4; ++e) acc[i][j][e] = 0.f;

    // staging granule geometry (8KB tile = 512 granules of 16B; 2 per thread)
    const int g0 = wave * 64 + lane;
    const int r0 = g0 >> 3, l0 = (g0 & 7) ^ (r0 & 7);
    const int g1 = g0 + 256;
    const int r1 = g1 >> 3, l1 = (g1 & 7) ^ (r1 & 7);

    for (int kt = 0; kt < nk; ++kt) {
        const int kk = kt * 64;
        GLOAD_LDS16(A + (size_t)(mb + r0) * lda + kk + l0 * 8, ldsA + wave * 1024);
        GLOAD_LDS16(A + (size_t)(mb + r1) * lda + kk + l1 * 8, ldsA + 4096 + wave * 1024);
        GLOAD_LDS16(W + (size_t)(nb + r0) * ldw + kk + l0 * 8, ldsB + wave * 1024);
        GLOAD_LDS16(W + (size_t)(nb + r1) * ldw + kk + l1 * 8, ldsB + 4096 + wave * 1024);
        __syncthreads();   // compiler drains vmcnt(0) before barrier
#pragma unroll
        for (int ks = 0; ks < 2; ++ks) {
            bf16x8 af[2], bfr[2];
#pragma unroll
            for (int mi = 0; mi < 2; ++mi) {
                int m_loc = wr * 32 + mi * 16 + lr;
                int gr = (ks * 4 + lk) ^ (m_loc & 7);
                af[mi] = *(const bf16x8*)(ldsA + m_loc * 128 + gr * 16);
            }
#pragma unroll
            for (int ni = 0; ni < 2; ++ni) {
                int n_loc = wc * 32 + ni * 16 + lr;
                int gr = (ks * 4 + lk) ^ (n_loc & 7);
                bfr[ni] = *(const bf16x8*)(ldsB + n_loc * 128 + gr * 16);
            }
#pragma unroll
            for (int mi = 0; mi < 2; ++mi)
#pragma unroll
                for (int ni = 0; ni < 2; ++ni)
                    acc[mi][ni] = __builtin_amdgcn_mfma_f32_16x16x32_bf16(
                        af[mi], bfr[ni], acc[mi][ni], 0, 0, 0);
        }
        __syncthreads();
    }

    // epilogue: C/D layout col = lane&15, row = (lane>>4)*4 + reg (m89-verified)
#pragma unroll
    for (int mi = 0; mi < 2; ++mi) {
#pragma unroll
        for (int ni = 0; ni < 2; ++ni) {
            const int n_g = nb + wc * 32 + ni * 16 + lr;
            const float bv = (n_g < Nreal) ? bias[n_g] : 0.f;
#pragma unroll
            for (int r = 0; r < 4; ++r) {
                const int m_g = mb + wr * 32 + mi * 16 + lk * 4 + r;
                float v = acc[mi][ni][r] + bv;
                if (RELU) v = fmaxf(v, 0.f);
                if (HASRES) v += bf2f(res[(size_t)m_g * ldo + n_g]);
                if (OUTF32) {
                    outF[(size_t)m_g * 768 + n_g] = v + addF[(size_t)m_g * 768 + n_g];
                } else {
                    outB[(size_t)m_g * ldo + n_g] = f2bf(v);
                }
            }
        }
    }
}

// ---------------------------------------------------------------------------
// L1 head: out[b][p] = -sum_d |feat[b][d] - protos[p][d]|
// Block: 32 rows x 64 protos, 256 threads (tp 16 x tr 16), thread tile 2x4.
// protos staged TRANSPOSED [d][p] so each thread reads 4 protos per b128.
// ---------------------------------------------------------------------------
__global__ __launch_bounds__(256) void l1_kernel(
    const float* __restrict__ feat, const float* __restrict__ protos,
    float* __restrict__ out)
{
    __shared__ float fs[32][97];     // [row][d], stride 97 (broadcast reads)
    __shared__ float ps_t[96][68];   // [d][proto], stride 68 (16B-aligned rows)
    const int tid = threadIdx.x;
    const int tp = tid & 15, tr = tid >> 4;
    const int rb = blockIdx.x * 32;
    const int pb = blockIdx.y * 64;

    float acc[2][4];
#pragma unroll
    for (int i = 0; i < 2; ++i)
#pragma unroll
        for (int j = 0; j < 4; ++j) acc[i][j] = 0.f;

    for (int d0 = 0; d0 < 768; d0 += 96) {
        __syncthreads();
        for (int i = tid; i < 32 * 96; i += 256) {
            int r = i / 96, c = i - r * 96;
            fs[r][c] = feat[(size_t)(rb + r) * 768 + d0 + c];
        }
        for (int i = tid; i < 64 * 96; i += 256) {
            int p = i / 96, c = i - p * 96;
            ps_t[c][p] = (pb + p < 200) ? protos[(size_t)(pb + p) * 768 + d0 + c] : 0.f;
        }
        __syncthreads();
#pragma unroll 4
        for (int d = 0; d < 96; ++d) {
            const float4 p4 = *(const float4*)&ps_t[d][tp * 4];
            const float pv[4] = {p4.x, p4.y, p4.z, p4.w};
            const float f0 = fs[tr * 2 + 0][d];
            const float f1 = fs[tr * 2 + 1][d];
#pragma unroll
            for (int j = 0; j < 4; ++j) {
                acc[0][j] += fabsf(f0 - pv[j]);
                acc[1][j] += fabsf(f1 - pv[j]);
            }
        }
    }
#pragma unroll
    for (int i = 0; i < 2; ++i)
#pragma unroll
        for (int j = 0; j < 4; ++j) {
            int p = pb + tp * 4 + j;
            if (p < 200)
                out[(size_t)(rb + tr * 2 + i) * 200 + p] = -acc[i][j];
        }
}

// ---------------------------------------------------------------------------
// Workspace layout (bytes). All sizes multiples of 256. Total ~24.5 MB.
// ---------------------------------------------------------------------------
static constexpr size_t OFF_XB   = 0;          // 2048x768 bf16
static constexpr size_t OFF_AWB  = 3145728;    // 768x768 bf16
static constexpr size_t OFF_WD0  = 4325376;    // 384x768
static constexpr size_t OFF_WD1  = 4915200;    // 192x384
static constexpr size_t OFF_WD2  = 5062656;    // 128x192 (N 96->128)
static constexpr size_t OFF_WD3  = 5111808;    // 64x128  (48->64, 96->128)
static constexpr size_t OFF_WU0  = 5128192;    // 128x64  (96->128, 48->64)
static constexpr size_t OFF_WU1  = 5144576;    // 192x128 (K 96->128)
static constexpr size_t OFF_WU2  = 5193728;    // 384x192
static constexpr size_t OFF_WU3  = 5341184;    // 768x384
static constexpr size_t OFF_H1   = 5931008;    // 2048x384 bf16
static constexpr size_t OFF_H2   = 7503872;    // 2048x192
static constexpr size_t OFF_H3   = 8290304;    // 2048x128 (96 pad 128)
static constexpr size_t OFF_H4   = 8814592;    // 2048x64  (48 pad 64)
static constexpr size_t OFF_U0   = 9076736;    // 2048x128
static constexpr size_t OFF_U1   = 9601024;    // 2048x192
static constexpr size_t OFF_U2   = 10387456;   // 2048x384
static constexpr size_t OFF_ADF  = 11960320;   // 2048x768 f32: x + x@aW.T + ab
static constexpr size_t OFF_FEAT = 18251776;   // 2048x768 f32: features

extern "C" void kernel_launch(void* const* d_in, const int* in_sizes, int n_in,
                              void* d_out, int out_size, void* d_ws, size_t ws_size,
                              hipStream_t stream) {
    const float* x      = (const float*)d_in[0];
    const float* aW     = (const float*)d_in[1];
    const float* ab     = (const float*)d_in[2];
    const float* protos = (const float*)d_in[3];
    const float* Wd[4]  = {(const float*)d_in[4], (const float*)d_in[6],
                           (const float*)d_in[8], (const float*)d_in[10]};
    const float* bd[4]  = {(const float*)d_in[5], (const float*)d_in[7],
                           (const float*)d_in[9], (const float*)d_in[11]};
    const float* Wu[4]  = {(const float*)d_in[12], (const float*)d_in[14],
                           (const float*)d_in[16], (const float*)d_in[18]};
    const float* bu[4]  = {(const float*)d_in[13], (const float*)d_in[15],
                           (const float*)d_in[17], (const float*)d_in[19]};
    float* out = (float*)d_out;
    char* ws = (char*)d_ws;

    u16* xb   = (u16*)(ws + OFF_XB);
    u16* aWb  = (u16*)(ws + OFF_AWB);
    u16* Wd0b = (u16*)(ws + OFF_WD0);
    u16* Wd1b = (u16*)(ws + OFF_WD1);
    u16* Wd2b = (u16*)(ws + OFF_WD2);
    u16* Wd3b = (u16*)(ws + OFF_WD3);
    u16* Wu0b = (u16*)(ws + OFF_WU0);
    u16* Wu1b = (u16*)(ws + OFF_WU1);
    u16* Wu2b = (u16*)(ws + OFF_WU2);
    u16* Wu3b = (u16*)(ws + OFF_WU3);
    u16* h1   = (u16*)(ws + OFF_H1);
    u16* h2   = (u16*)(ws + OFF_H2);
    u16* h3   = (u16*)(ws + OFF_H3);
    u16* h4   = (u16*)(ws + OFF_H4);
    u16* u0   = (u16*)(ws + OFF_U0);
    u16* u1   = (u16*)(ws + OFF_U1);
    u16* u2   = (u16*)(ws + OFF_U2);
    float* adF  = (float*)(ws + OFF_ADF);
    float* feat = (float*)(ws + OFF_FEAT);

    // --- 1. convert/pad everything to bf16 in one launch ---
    CvtTab tab;
    int blk = 0;
    auto set = [&](int i, const float* s, u16* d, int N, int K, int Np, int Kp) {
        tab.t[i] = {s, d, N, K, Np, Kp, blk};
        blk += (Np * Kp + 255) / 256;
    };
    set(0, x,     xb,   2048, 768, 2048, 768);
    set(1, aW,    aWb,  768,  768, 768,  768);
    set(2, Wd[0], Wd0b, 384,  768, 384,  768);
    set(3, Wd[1], Wd1b, 192,  384, 192,  384);
    set(4, Wd[2], Wd2b, 96,   192, 128,  192);
    set(5, Wd[3], Wd3b, 48,   96,  64,   128);
    set(6, Wu[0], Wu0b, 96,   48,  128,  64);
    set(7, Wu[1], Wu1b, 192,  96,  192,  128);
    set(8, Wu[2], Wu2b, 384,  192, 384,  192);
    set(9, Wu[3], Wu3b, 768,  384, 768,  384);
    cvt_all<<<blk, 256, 0, stream>>>(tab);

    // --- 2. GEMM chain (grid = (M/64, Npad/64), nk = Kpad/64) ---
    // adapter: adF = x + x@aW.T + ab
    gemm_k<0,0,1><<<dim3(32,12), 256, 0, stream>>>(xb, 768, aWb, 768, ab, 768,
        nullptr, 0, nullptr, adF, x, 12);
    // down path
    gemm_k<1,0,0><<<dim3(32,6), 256, 0, stream>>>(xb, 768, Wd0b, 768, bd[0], 384,
        h1, 384, nullptr, nullptr, nullptr, 12);
    gemm_k<1,0,0><<<dim3(32,3), 256, 0, stream>>>(h1, 384, Wd1b, 384, bd[1], 192,
        h2, 192, nullptr, nullptr, nullptr, 6);
    gemm_k<1,0,0><<<dim3(32,2), 256, 0, stream>>>(h2, 192, Wd2b, 192, bd[2], 96,
        h3, 128, nullptr, nullptr, nullptr, 3);
    gemm_k<1,0,0><<<dim3(32,1), 256, 0, stream>>>(h3, 128, Wd3b, 128, bd[3], 48,
        h4, 64, nullptr, nullptr, nullptr, 2);
    // up path (residual skip-adds folded into producer epilogues)
    gemm_k<1,1,0><<<dim3(32,2), 256, 0, stream>>>(h4, 64, Wu0b, 64, bu[0], 96,
        u0, 128, h3, nullptr, nullptr, 1);          // u0 = relu(.)+h3
    gemm_k<1,1,0><<<dim3(32,3), 256, 0, stream>>>(u0, 128, Wu1b, 128, bu[1], 192,
        u1, 192, h2, nullptr, nullptr, 2);          // u1 = relu(.)+h2
    gemm_k<1,0,0><<<dim3(32,6), 256, 0, stream>>>(u1, 192, Wu2b, 192, bu[2], 384,
        u2, 384, nullptr, nullptr, nullptr, 3);
    // u3: feat = relu(u2@Wu3.T + bu3) + adF
    gemm_k<1,0,1><<<dim3(32,12), 256, 0, stream>>>(u2, 384, Wu3b, 384, bu[3], 768,
        nullptr, 0, nullptr, feat, adF, 6);

    // --- 3. L1 prototype head ---
    l1_kernel<<<dim3(64, 4), 256, 0, stream>>>(feat, protos, out);
}

// Round 2
// 110.863 us; speedup vs baseline: 1.6122x; 1.6122x over previous
//
#include <hip/hip_runtime.h>

typedef __attribute__((ext_vector_type(8))) __bf16 bf16x8;
typedef __attribute__((ext_vector_type(4))) float f32x4;
typedef unsigned short u16;

__device__ __forceinline__ float bf2f(u16 h) {
    return __uint_as_float(((unsigned int)h) << 16);
}
__device__ __forceinline__ u16 f2bf(float f) {
    unsigned int u = __float_as_uint(f);
    u += 0x7fffu + ((u >> 16) & 1u);   // RNE
    return (u16)(u >> 16);
}

#define GLOAD_LDS16(gsrc, ldst)                                                          \
    __builtin_amdgcn_global_load_lds(                                                    \
        (__attribute__((address_space(1))) unsigned int*)(gsrc),                         \
        (__attribute__((address_space(3))) unsigned int*)(ldst), 16, 0, 0)

// ---------------------------------------------------------------------------
// Fused f32 -> bf16 convert with zero-padding to (Npad, Kpad)
// ---------------------------------------------------------------------------
struct CvtDesc { const float* src; u16* dst; int N, K, Npad, Kpad, blk0; };
struct CvtTab { CvtDesc t[10]; };

__global__ __launch_bounds__(256) void cvt_all(CvtTab tab) {
    int b = blockIdx.x;
    int ti = 0;
#pragma unroll
    for (int j = 1; j < 10; ++j)
        if (b >= tab.t[j].blk0) ti = j;
    const CvtDesc c = tab.t[ti];
    long i = (long)(b - c.blk0) * 256 + threadIdx.x;
    long tot = (long)c.Npad * c.Kpad;
    if (i >= tot) return;
    int n = (int)(i / c.Kpad);
    int k = (int)(i - (long)n * c.Kpad);
    float v = (n < c.N && k < c.K) ? c.src[(long)n * c.K + k] : 0.f;
    c.dst[i] = f2bf(v);
}

// ---------------------------------------------------------------------------
// bf16 MFMA GEMM: out[m][n] = epilogue( sum_k A[m][k] * W[n][k] + bias[n] )
// BM=BN=BK=64, 256 threads (4 waves as 2x2), 16x16x32 MFMA.
// LDS tiles [64][64] bf16, XOR-swizzled granules (byte ^= (row&7)<<4) via
// pre-swizzled global source + linear global_load_lds dest (rule 21).
// ---------------------------------------------------------------------------
template<int RELU, int HASRES, int OUTF32>
__global__ __launch_bounds__(256) void gemm_k(
    const u16* __restrict__ A, int lda,
    const u16* __restrict__ W, int ldw,
    const float* __restrict__ bias, int Nreal,
    u16* __restrict__ outB, int ldo,
    const u16* __restrict__ res,
    float* __restrict__ outF, const float* __restrict__ addF,
    int nk)
{
    __shared__ __align__(16) char lds[16384];
    char* ldsA = lds;
    char* ldsB = lds + 8192;

    const int tid  = threadIdx.x;
    const int wave = tid >> 6;
    const int lane = tid & 63;
    const int wr = wave >> 1, wc = wave & 1;
    const int lr = lane & 15, lk = lane >> 4;
    const int mb = blockIdx.x * 64;
    const int nb = blockIdx.y * 64;

    f32x4 acc[2][2];
#pragma unroll
    for (int i = 0; i < 2; ++i)
#pragma unroll
        for (int j = 0; j < 2; ++j)
#pragma unroll
            for (int e = 0; e < 4; ++e) acc[i][j][e] = 0.f;

    // staging granule geometry (8KB tile = 512 granules of 16B; 2 per thread)
    const int g0 = wave * 64 + lane;
    const int r0 = g0 >> 3, l0 = (g0 & 7) ^ (r0 & 7);
    const int g1 = g0 + 256;
    const int r1 = g1 >> 3, l1 = (g1 & 7) ^ (r1 & 7);

    for (int kt = 0; kt < nk; ++kt) {
        const int kk = kt * 64;
        GLOAD_LDS16(A + (size_t)(mb + r0) * lda + kk + l0 * 8, ldsA + wave * 1024);
        GLOAD_LDS16(A + (size_t)(mb + r1) * lda + kk + l1 * 8, ldsA + 4096 + wave * 1024);
        GLOAD_LDS16(W + (size_t)(nb + r0) * ldw + kk + l0 * 8, ldsB + wave * 1024);
        GLOAD_LDS16(W + (size_t)(nb + r1) * ldw + kk + l1 * 8, ldsB + 4096 + wave * 1024);
        __syncthreads();   // compiler drains vmcnt(0) before barrier
#pragma unroll
        for (int ks = 0; ks < 2; ++ks) {
            bf16x8 af[2], bfr[2];
#pragma unroll
            for (int mi = 0; mi < 2; ++mi) {
                int m_loc = wr * 32 + mi * 16 + lr;
                int gr = (ks * 4 + lk) ^ (m_loc & 7);
                af[mi] = *(const bf16x8*)(ldsA + m_loc * 128 + gr * 16);
            }
#pragma unroll
            for (int ni = 0; ni < 2; ++ni) {
                int n_loc = wc * 32 + ni * 16 + lr;
                int gr = (ks * 4 + lk) ^ (n_loc & 7);
                bfr[ni] = *(const bf16x8*)(ldsB + n_loc * 128 + gr * 16);
            }
#pragma unroll
            for (int mi = 0; mi < 2; ++mi)
#pragma unroll
                for (int ni = 0; ni < 2; ++ni)
                    acc[mi][ni] = __builtin_amdgcn_mfma_f32_16x16x32_bf16(
                        af[mi], bfr[ni], acc[mi][ni], 0, 0, 0);
        }
        __syncthreads();
    }

    // epilogue: C/D layout col = lane&15, row = (lane>>4)*4 + reg (m89-verified)
#pragma unroll
    for (int mi = 0; mi < 2; ++mi) {
#pragma unroll
        for (int ni = 0; ni < 2; ++ni) {
            const int n_g = nb + wc * 32 + ni * 16 + lr;
            const float bv = (n_g < Nreal) ? bias[n_g] : 0.f;
#pragma unroll
            for (int r = 0; r < 4; ++r) {
                const int m_g = mb + wr * 32 + mi * 16 + lk * 4 + r;
                float v = acc[mi][ni][r] + bv;
                if (RELU) v = fmaxf(v, 0.f);
                if (HASRES) v += bf2f(res[(size_t)m_g * ldo + n_g]);
                if (OUTF32) {
                    outF[(size_t)m_g * 768 + n_g] = v + addF[(size_t)m_g * 768 + n_g];
                } else {
                    outB[(size_t)m_g * ldo + n_g] = f2bf(v);
                }
            }
        }
    }
}

// ---------------------------------------------------------------------------
// L1 head v2: out[b][p] = -sum_d |feat[b][d] - protos[p][d]|
// Grid (64 row-blocks, 4 proto-blocks, 4 d-chunks) = 1024 blocks, 256 thr.
// Block: 32 rows x 64 protos x 192 d (two 96-d LDS stages).
// Thread: 2 rows x 4 protos, d vectorized by 4 (all LDS reads b128).
// Partials combined via atomicAdd(-acc) into zeroed out.
// ---------------------------------------------------------------------------
__global__ __launch_bounds__(256) void l1_kernel(
    const float* __restrict__ feat, const float* __restrict__ protos,
    float* __restrict__ out)
{
    __shared__ float fs[32][104];   // [row][d], stride 104 (16B-aligned, 2-way max)
    __shared__ float pt[96][68];    // [d][proto], stride 68 (16B-aligned)
    const int tid = threadIdx.x;
    const int tp = tid & 15, tr = tid >> 4;
    const int rb = blockIdx.x * 32;
    const int pb = blockIdx.y * 64;
    const int dbase = blockIdx.z * 192;

    float acc[2][4];
#pragma unroll
    for (int i = 0; i < 2; ++i)
#pragma unroll
        for (int j = 0; j < 4; ++j) acc[i][j] = 0.f;

    const int sp = tid & 63;        // staging proto id
    const int sq = tid >> 6;        // staging d-quad phase (0..3)
    const int gp = pb + sp;

    for (int s = 0; s < 2; ++s) {
        const int db = dbase + s * 96;
        __syncthreads();
        // stage fs: 32 rows x 96 d = 768 float4s, 3 per thread (coalesced)
#pragma unroll
        for (int t = 0; t < 3; ++t) {
            int i = tid + t * 256;
            int row = i / 24, q = i - row * 24;
            *(float4*)&fs[row][q * 4] =
                *(const float4*)&feat[(size_t)(rb + row) * 768 + db + q * 4];
        }
        // stage pt transposed: thread owns proto sp, d-quads sq+4t
        // (lane-consecutive p on writes -> conflict-free)
#pragma unroll
        for (int t = 0; t < 6; ++t) {
            int dq = sq + t * 4;    // 0..23
            float4 v;
            if (gp < 200)
                v = *(const float4*)&protos[(size_t)gp * 768 + db + dq * 4];
            else
                v = float4{0.f, 0.f, 0.f, 0.f};
            pt[dq * 4 + 0][sp] = v.x;
            pt[dq * 4 + 1][sp] = v.y;
            pt[dq * 4 + 2][sp] = v.z;
            pt[dq * 4 + 3][sp] = v.w;
        }
        __syncthreads();
#pragma unroll 4
        for (int d = 0; d < 96; d += 4) {
            const float4 f0 = *(const float4*)&fs[tr * 2 + 0][d];
            const float4 f1 = *(const float4*)&fs[tr * 2 + 1][d];
            const float4 q0 = *(const float4*)&pt[d + 0][tp * 4];
            const float4 q1 = *(const float4*)&pt[d + 1][tp * 4];
            const float4 q2 = *(const float4*)&pt[d + 2][tp * 4];
            const float4 q3 = *(const float4*)&pt[d + 3][tp * 4];
            const float fa[2][4] = {{f0.x, f0.y, f0.z, f0.w},
                                    {f1.x, f1.y, f1.z, f1.w}};
            const float pv[4][4] = {{q0.x, q0.y, q0.z, q0.w},
                                    {q1.x, q1.y, q1.z, q1.w},
                                    {q2.x, q2.y, q2.z, q2.w},
                                    {q3.x, q3.y, q3.z, q3.w}};
#pragma unroll
            for (int k = 0; k < 4; ++k)
#pragma unroll
                for (int j = 0; j < 4; ++j) {
                    acc[0][j] += fabsf(fa[0][k] - pv[k][j]);
                    acc[1][j] += fabsf(fa[1][k] - pv[k][j]);
                }
        }
    }
#pragma unroll
    for (int i = 0; i < 2; ++i)
#pragma unroll
        for (int j = 0; j < 4; ++j) {
            int p = pb + tp * 4 + j;
            if (p < 200)
                atomicAdd(&out[(size_t)(rb + tr * 2 + i) * 200 + p], -acc[i][j]);
        }
}

// ---------------------------------------------------------------------------
// Workspace layout (bytes). All sizes multiples of 256. Total ~24.5 MB.
// ---------------------------------------------------------------------------
static constexpr size_t OFF_XB   = 0;          // 2048x768 bf16
static constexpr size_t OFF_AWB  = 3145728;    // 768x768 bf16
static constexpr size_t OFF_WD0  = 4325376;    // 384x768
static constexpr size_t OFF_WD1  = 4915200;    // 192x384
static constexpr size_t OFF_WD2  = 5062656;    // 128x192 (N 96->128)
static constexpr size_t OFF_WD3  = 5111808;    // 64x128  (48->64, 96->128)
static constexpr size_t OFF_WU0  = 5128192;    // 128x64  (96->128, 48->64)
static constexpr size_t OFF_WU1  = 5144576;    // 192x128 (K 96->128)
static constexpr size_t OFF_WU2  = 5193728;    // 384x192
static constexpr size_t OFF_WU3  = 5341184;    // 768x384
static constexpr size_t OFF_H1   = 5931008;    // 2048x384 bf16
static constexpr size_t OFF_H2   = 7503872;    // 2048x192
static constexpr size_t OFF_H3   = 8290304;    // 2048x128 (96 pad 128)
static constexpr size_t OFF_H4   = 8814592;    // 2048x64  (48 pad 64)
static constexpr size_t OFF_U0   = 9076736;    // 2048x128
static constexpr size_t OFF_U1   = 9601024;    // 2048x192
static constexpr size_t OFF_U2   = 10387456;   // 2048x384
static constexpr size_t OFF_ADF  = 11960320;   // 2048x768 f32: x + x@aW.T + ab
static constexpr size_t OFF_FEAT = 18251776;   // 2048x768 f32: features

extern "C" void kernel_launch(void* const* d_in, const int* in_sizes, int n_in,
                              void* d_out, int out_size, void* d_ws, size_t ws_size,
                              hipStream_t stream) {
    const float* x      = (const float*)d_in[0];
    const float* aW     = (const float*)d_in[1];
    const float* ab     = (const float*)d_in[2];
    const float* protos = (const float*)d_in[3];
    const float* Wd[4]  = {(const float*)d_in[4], (const float*)d_in[6],
                           (const float*)d_in[8], (const float*)d_in[10]};
    const float* bd[4]  = {(const float*)d_in[5], (const float*)d_in[7],
                           (const float*)d_in[9], (const float*)d_in[11]};
    const float* Wu[4]  = {(const float*)d_in[12], (const float*)d_in[14],
                           (const float*)d_in[16], (const float*)d_in[18]};
    const float* bu[4]  = {(const float*)d_in[13], (const float*)d_in[15],
                           (const float*)d_in[17], (const float*)d_in[19]};
    float* out = (float*)d_out;
    char* ws = (char*)d_ws;

    u16* xb   = (u16*)(ws + OFF_XB);
    u16* aWb  = (u16*)(ws + OFF_AWB);
    u16* Wd0b = (u16*)(ws + OFF_WD0);
    u16* Wd1b = (u16*)(ws + OFF_WD1);
    u16* Wd2b = (u16*)(ws + OFF_WD2);
    u16* Wd3b = (u16*)(ws + OFF_WD3);
    u16* Wu0b = (u16*)(ws + OFF_WU0);
    u16* Wu1b = (u16*)(ws + OFF_WU1);
    u16* Wu2b = (u16*)(ws + OFF_WU2);
    u16* Wu3b = (u16*)(ws + OFF_WU3);
    u16* h1   = (u16*)(ws + OFF_H1);
    u16* h2   = (u16*)(ws + OFF_H2);
    u16* h3   = (u16*)(ws + OFF_H3);
    u16* h4   = (u16*)(ws + OFF_H4);
    u16* u0   = (u16*)(ws + OFF_U0);
    u16* u1   = (u16*)(ws + OFF_U1);
    u16* u2   = (u16*)(ws + OFF_U2);
    float* adF  = (float*)(ws + OFF_ADF);
    float* feat = (float*)(ws + OFF_FEAT);

    // --- 1. convert/pad everything to bf16 in one launch ---
    CvtTab tab;
    int blk = 0;
    auto set = [&](int i, const float* s, u16* d, int N, int K, int Np, int Kp) {
        tab.t[i] = {s, d, N, K, Np, Kp, blk};
        blk += (Np * Kp + 255) / 256;
    };
    set(0, x,     xb,   2048, 768, 2048, 768);
    set(1, aW,    aWb,  768,  768, 768,  768);
    set(2, Wd[0], Wd0b, 384,  768, 384,  768);
    set(3, Wd[1], Wd1b, 192,  384, 192,  384);
    set(4, Wd[2], Wd2b, 96,   192, 128,  192);
    set(5, Wd[3], Wd3b, 48,   96,  64,   128);
    set(6, Wu[0], Wu0b, 96,   48,  128,  64);
    set(7, Wu[1], Wu1b, 192,  96,  192,  128);
    set(8, Wu[2], Wu2b, 384,  192, 384,  192);
    set(9, Wu[3], Wu3b, 768,  384, 768,  384);
    cvt_all<<<blk, 256, 0, stream>>>(tab);

    // --- 2. GEMM chain (grid = (M/64, Npad/64), nk = Kpad/64) ---
    // adapter: adF = x + x@aW.T + ab
    gemm_k<0,0,1><<<dim3(32,12), 256, 0, stream>>>(xb, 768, aWb, 768, ab, 768,
        nullptr, 0, nullptr, adF, x, 12);
    // down path
    gemm_k<1,0,0><<<dim3(32,6), 256, 0, stream>>>(xb, 768, Wd0b, 768, bd[0], 384,
        h1, 384, nullptr, nullptr, nullptr, 12);
    gemm_k<1,0,0><<<dim3(32,3), 256, 0, stream>>>(h1, 384, Wd1b, 384, bd[1], 192,
        h2, 192, nullptr, nullptr, nullptr, 6);
    gemm_k<1,0,0><<<dim3(32,2), 256, 0, stream>>>(h2, 192, Wd2b, 192, bd[2], 96,
        h3, 128, nullptr, nullptr, nullptr, 3);
    gemm_k<1,0,0><<<dim3(32,1), 256, 0, stream>>>(h3, 128, Wd3b, 128, bd[3], 48,
        h4, 64, nullptr, nullptr, nullptr, 2);
    // up path (residual skip-adds folded into producer epilogues)
    gemm_k<1,1,0><<<dim3(32,2), 256, 0, stream>>>(h4, 64, Wu0b, 64, bu[0], 96,
        u0, 128, h3, nullptr, nullptr, 1);          // u0 = relu(.)+h3
    gemm_k<1,1,0><<<dim3(32,3), 256, 0, stream>>>(u0, 128, Wu1b, 128, bu[1], 192,
        u1, 192, h2, nullptr, nullptr, 2);          // u1 = relu(.)+h2
    gemm_k<1,0,0><<<dim3(32,6), 256, 0, stream>>>(u1, 192, Wu2b, 192, bu[2], 384,
        u2, 384, nullptr, nullptr, nullptr, 3);
    // u3: feat = relu(u2@Wu3.T + bu3) + adF
    gemm_k<1,0,1><<<dim3(32,12), 256, 0, stream>>>(u2, 384, Wu3b, 384, bu[3], 768,
        nullptr, 0, nullptr, feat, adF, 6);

    // --- 3. L1 prototype head: zero out, then atomic partial sums ---
    hipMemsetAsync(d_out, 0, (size_t)2048 * 200 * sizeof(float), stream);
    l1_kernel<<<dim3(64, 4, 4), 256, 0, stream>>>(feat, protos, out);
}